// Round 15
// baseline (105.561 us; speedup 1.0000x reference)
//
#include <hip/hip_runtime.h>
#include <math.h>

// DiscriminativeLoss: N=1e6 x D=32 fp32, K=64, scalar out.
// R15 = R13 (62.0us best) with pass1 rebuilt as coalesced-stream -> LDS tile
// -> LDS gather (R5's shape minus its two diseases: no global atomics, and
// a 36-float padded row so gather banks = (4*idx+4*sub)%32 spread randomly;
// the write pattern sits exactly on the b128 8-cycle floor).
// 512 thr / 512 pts per block: label stays in a register (no s_lab), feature
// loads issued BEFORE histogram/scan/scatter so HBM latency hides under the
// sort. HBM access order becomes pure streaming (R14 showed the scattered
// gather order, not chain depth, is pass1's remaining deficit).
// reduce1/pass2/final = R13 verbatim. Lessons: merges must keep grid
// saturated (R1/R10/R11); no returning-atomic tails (R6); no volume global
// atomics (R5: write-through); one variable per round (R9/R10).

#define EPS_F 1e-8f
constexpr int D = 32;
constexpr int K = 64;
constexpr int NPTS = 512;                // points per pass1 block (512 thr)
constexpr int RSTRIDE = 36;              // padded LDS row stride (floats)
constexpr int P1 = K * D + K;            // 2112: 2048 sums + 64 counts
constexpr int NCH = 64;                  // reduction chunks
constexpr int NBLK2 = 2048;              // pass2 blocks
constexpr int MPAD = 40;                 // pass2 LDS means row stride

// dynamic-LDS partition (floats): tile | idx(as u16 in 256 floats) | hist|pref|cur
constexpr int L_TILE = NPTS * RSTRIDE;           // 18432 floats = 73728 B
constexpr int L_IDX  = L_TILE;                   // 512 u16 = 256 floats
constexpr int L_HIST = L_IDX + NPTS / 2;
constexpr int L_PREF = L_HIST + K;
constexpr int L_CUR  = L_PREF + K;
constexpr int L_TOTAL = L_CUR + K;               // 18944 floats = 75776 B

// ---------------- pass 1: stream->LDS tile, sort, LDS gather ---------------
__global__ __launch_bounds__(512) void pass1_kernel(
    const float* __restrict__ feat, const int* __restrict__ lab,
    float* __restrict__ part1, float* __restrict__ sums, int N)
{
    extern __shared__ float smem[];
    float*          s_tile = smem;
    unsigned short* s_idx  = (unsigned short*)(smem + L_IDX);
    int*            s_hist = (int*)(smem + L_HIST);
    int*            s_pref = (int*)(smem + L_PREF);
    int*            s_cur  = (int*)(smem + L_CUR);

    const int tid = threadIdx.x;
    const long long base = (long long)blockIdx.x * NPTS;
    int npts = (int)((long long)N - base);
    if (npts > NPTS) npts = NPTS;
    const int nf4 = npts * 8;                  // float4s in tile

    if (blockIdx.x == 0)                       // zero global accumulator
        for (int e = tid; e < P1; e += 512) sums[e] = 0.f;

    // (1) issue label load, then 8 coalesced feature float4 loads -> regs.
    //     HBM latency hides under the sort phases below.
    const int myl = (tid < npts) ? lab[base + tid] : -1;
    float4 st[8];
    const float4* fsrc = (const float4*)(feat + base * D);
    #pragma unroll
    for (int u = 0; u < 8; u++) {
        const int g = tid + u * 512;           // f4 index, coalesced
        if (g < nf4) st[u] = fsrc[g];
    }

    if (tid < K) s_hist[tid] = 0;
    __syncthreads();
    if (myl >= 0) atomicAdd(&s_hist[myl], 1);  // histogram (waits labels only)
    __syncthreads();

    // exclusive prefix over 64 bins (wave 0)
    if (tid < 64) {
        const int h = s_hist[tid];
        int v = h;
        for (int off = 1; off < 64; off <<= 1) {
            const int up = __shfl_up(v, off);
            if (tid >= off) v += up;
        }
        s_pref[tid] = v - h;
        s_cur[tid]  = v - h;
    }
    __syncthreads();

    // scatter sorted indices (1 int atomic per point)
    if (myl >= 0) {
        const int pos = atomicAdd(&s_cur[myl], 1);
        s_idx[pos] = (unsigned short)tid;
    }

    // land the staged tile in padded LDS (row g>>3, col4 g&7)
    #pragma unroll
    for (int u = 0; u < 8; u++) {
        const int g = tid + u * 512;
        if (g < nf4)
            *(float4*)&s_tile[(g >> 3) * RSTRIDE + (g & 7) * 4] = st[u];
    }
    __syncthreads();

    // gather from LDS: thread = (cluster k = tid>>3, sub = tid&7)
    const int k = tid >> 3, sub = tid & 7;
    const int start = s_pref[k], len = s_hist[k];
    float4 a = {0.f, 0.f, 0.f, 0.f};
    int i = 0;
    for (; i + 4 <= len; i += 4) {
        const int i0 = s_idx[start + i + 0];
        const int i1 = s_idx[start + i + 1];
        const int i2 = s_idx[start + i + 2];
        const int i3 = s_idx[start + i + 3];
        const float4 x0 = *(const float4*)&s_tile[i0 * RSTRIDE + sub * 4];
        const float4 x1 = *(const float4*)&s_tile[i1 * RSTRIDE + sub * 4];
        const float4 x2 = *(const float4*)&s_tile[i2 * RSTRIDE + sub * 4];
        const float4 x3 = *(const float4*)&s_tile[i3 * RSTRIDE + sub * 4];
        a.x += (x0.x + x1.x) + (x2.x + x3.x);
        a.y += (x0.y + x1.y) + (x2.y + x3.y);
        a.z += (x0.z + x1.z) + (x2.z + x3.z);
        a.w += (x0.w + x1.w) + (x2.w + x3.w);
    }
    for (; i < len; ++i) {
        const int i0 = s_idx[start + i];
        const float4 x0 = *(const float4*)&s_tile[i0 * RSTRIDE + sub * 4];
        a.x += x0.x; a.y += x0.y; a.z += x0.z; a.w += x0.w;
    }
    float* outp = part1 + (long long)blockIdx.x * P1;
    ((float4*)outp)[tid] = a;                  // cell k*32 + sub*4 == f4 tid
    if (tid < K) outp[K * D + tid] = (float)s_hist[tid];
}

// ------- reduce: chunk-partials -> fire-and-forget atomics into sums -------
__global__ __launch_bounds__(256) void reduce1_kernel(
    const float* __restrict__ part1, float* __restrict__ sums,
    int chsz, int nblk1)
{
    const int e = blockIdx.x * 256 + threadIdx.x;
    if (e >= P1) return;
    const int y = blockIdx.y;
    const int b0 = y * chsz;
    int b1 = b0 + chsz; if (b1 > nblk1) b1 = nblk1;
    float s = 0.f;
    for (int b = b0; b < b1; b++) s += part1[(long long)b * P1 + e];
    atomicAdd(&sums[e], s);                   // non-returning, 64 contenders
}

// ---------------- pass 2: means-from-sums prologue + hinge + block0 epi ----
__global__ __launch_bounds__(256, 4) void pass2_kernel(
    const float* __restrict__ feat, const int* __restrict__ lab,
    const float* __restrict__ sums,
    float* __restrict__ hpart, float* __restrict__ ir, int N)
{
    __shared__ float s_m[K * MPAD];   // padded means, 10 KB
    __shared__ float s_ic[K];
    __shared__ float s_red[256];
    const int tid = threadIdx.x;

    for (int e = tid; e < K * D; e += 256) {          // means = sums / cnt
        const float c = sums[K * D + (e >> 5)];       // broadcast line, L2-hot
        s_m[(e >> 5) * MPAD + (e & 31)] = sums[e] / fmaxf(c, 1.0f);
    }
    if (tid < K) s_ic[tid] = 1.0f / fmaxf(sums[K * D + tid], 1.0f);
    __syncthreads();

    float racc = 0.f;
    const long long stride = (long long)NBLK2 * 256;
    for (long long p = (long long)blockIdx.x * 256 + tid; p < N; p += stride) {
        const int l = lab[p];
        const float4* frow = (const float4*)(feat + p * D);
        float4 fv[8];
        #pragma unroll
        for (int j = 0; j < 8; j++) fv[j] = frow[j];   // 8 loads in flight
        const float* mrow = s_m + l * MPAD;
        float d2 = 0.f;
        #pragma unroll
        for (int j = 0; j < 8; j++) {
            const float4 mv = *(const float4*)(mrow + j * 4);
            const float dx = fv[j].x - mv.x + EPS_F;
            const float dy = fv[j].y - mv.y + EPS_F;
            const float dz = fv[j].z - mv.z + EPS_F;
            const float dw = fv[j].w - mv.w + EPS_F;
            d2 += dx * dx + dy * dy + dz * dz + dw * dw;
        }
        const float h = fmaxf(sqrtf(d2) - 1.5f, 0.f);  // INTRA_MARGIN_USED
        racc += h * h * s_ic[l];
    }
    s_red[tid] = racc;
    __syncthreads();
    for (int st = 128; st; st >>= 1) { if (tid < st) s_red[tid] += s_red[tid + st]; __syncthreads(); }
    if (tid == 0) hpart[blockIdx.x] = s_red[0];

    if (blockIdx.x != 0) return;
    // ---- block 0 epilogue: inter + reg from s_m (overlaps other blocks) ----
    __syncthreads();
    float mj[32];
    const int j = tid & 63;
    #pragma unroll
    for (int d = 0; d < 32; d++) mj[d] = s_m[j * MPAD + d];
    float isum = 0.f;
    const int igrp = tid >> 6;        // 0..3, 16 i's each; i wave-uniform
    for (int ii = 0; ii < 16; ii++) {
        const int i = igrp * 16 + ii;
        const float4* srow = (const float4*)(s_m + i * MPAD);
        float d2 = 0.f;
        #pragma unroll
        for (int q = 0; q < 8; q++) {
            const float4 mv = srow[q];
            const float b0 = mv.x - mj[q * 4 + 0] + EPS_F;
            const float b1 = mv.y - mj[q * 4 + 1] + EPS_F;
            const float b2 = mv.z - mj[q * 4 + 2] + EPS_F;
            const float b3 = mv.w - mj[q * 4 + 3] + EPS_F;
            d2 += b0 * b0 + b1 * b1 + b2 * b2 + b3 * b3;
        }
        if (i != j) {
            const float h = fmaxf(1.0f - sqrtf(d2), 0.f);  // 2*margin - pd
            isum += h * h;
        }
    }
    s_red[tid] = isum;
    __syncthreads();
    for (int st = 128; st; st >>= 1) { if (tid < st) s_red[tid] += s_red[tid + st]; __syncthreads(); }
    if (tid == 0) ir[0] = s_red[0] * (1.0f / ((K - 1) * K));
    __syncthreads();

    float r = 0.f;
    if (tid < 64) {
        float d2 = 0.f;
        #pragma unroll
        for (int d = 0; d < 32; d++) { const float t = mj[d] + EPS_F; d2 += t * t; }
        r = sqrtf(d2);
    }
    s_red[tid] = r;
    __syncthreads();
    for (int st = 128; st; st >>= 1) { if (tid < st) s_red[tid] += s_red[tid + st]; __syncthreads(); }
    if (tid == 0) ir[1] = s_red[0] * (1.0f / K);
}

// ---------------- final: hpart sum + combine --------------------------------
__global__ __launch_bounds__(256) void final_kernel(
    const float* __restrict__ hpart, const float* __restrict__ ir,
    float* __restrict__ out)
{
    __shared__ float s_red[256];
    const int tid = threadIdx.x;
    float hs = 0.f;
    for (int b = tid; b < NBLK2; b += 256) hs += hpart[b];
    s_red[tid] = hs;
    __syncthreads();
    for (int st = 128; st; st >>= 1) { if (tid < st) s_red[tid] += s_red[tid + st]; __syncthreads(); }
    if (tid == 0) out[0] = s_red[0] * (1.0f / K) + ir[0] + 0.001f * ir[1];
}

extern "C" void kernel_launch(void* const* d_in, const int* in_sizes, int n_in,
                              void* d_out, int out_size, void* d_ws, size_t ws_size,
                              hipStream_t stream)
{
    const float* feat = (const float*)d_in[0];
    const int*   lab  = (const int*)d_in[1];
    const int N = in_sizes[1];            // 1e6; D=32, K=64 fixed by reference

    float* ws = (float*)d_ws;

    const int nblk1 = (N + NPTS - 1) / NPTS;         // 1954
    const int chsz  = (nblk1 + NCH - 1) / NCH;       // 31

    float* sums  = ws;                               // P1 (sums + counts)
    float* ir    = sums + P1;                        // 2 (+pad 2)
    float* hpart = ir + 4;                           // NBLK2
    float* part1 = hpart + NBLK2;                    // nblk1*P1

    pass1_kernel<<<nblk1, 512, L_TOTAL * 4, stream>>>(feat, lab, part1, sums, N);
    reduce1_kernel<<<dim3((P1 + 255) / 256, NCH), 256, 0, stream>>>(part1, sums, chsz, nblk1);
    pass2_kernel<<<NBLK2, 256, 0, stream>>>(feat, lab, sums, hpart, ir, N);
    final_kernel<<<1, 256, 0, stream>>>(hpart, ir, (float*)d_out);
}

// Round 16
// 61.962 us; speedup vs baseline: 1.7036x; 1.7036x over previous
//
#include <hip/hip_runtime.h>
#include <math.h>

// DiscriminativeLoss: N=1e6 x D=32 fp32, K=64, scalar out.
// R16 = R13 VERBATIM (62.0us, proven best) — reverting R15's LDS-tile pass1
// (105us: 819K bank conflicts + compiler sank the prefetch to the landing
// site, VGPR=20 proves staging regs were never held across the sort).
// Final architecture:
//   pass1: block-local counting sort + per-cluster register gather (4.9TB/s)
//   reduce1: coalesced chunk reduce -> fire-and-forget atomics into sums
//   pass2: lane-owns-point hinge (6.6TB/s, L3-assisted) + block0 inter/reg
//   final: 2048-partial sum + combine
// Closed branches (measured): LDS tiling of pass1 gather (R5/R15); kernel
// merges that starve the grid (R1/R10/R11); returning-atomic tails (R6);
// per-thread-volume global atomics (R5); deeper unroll of gather (R14,
// neutral); NPTS != 1024 (R7/R10).

#define EPS_F 1e-8f
constexpr int D = 32;
constexpr int K = 64;
constexpr int NPTS = 1024;               // points per pass1 block
constexpr int P1 = K * D + K;            // 2112: 2048 sums + 64 counts
constexpr int NCH = 64;                  // reduction chunks
constexpr int NBLK2 = 2048;              // pass2 blocks
constexpr int MPAD = 40;                 // LDS means row stride

// ---------------- pass 1: sort-by-label, register segment sums -------------
__global__ __launch_bounds__(256, 4) void pass1_kernel(
    const float* __restrict__ feat, const int* __restrict__ lab,
    float* __restrict__ part1, float* __restrict__ sums, int N)
{
    __shared__ int            s_lab[NPTS];
    __shared__ unsigned short s_idx[NPTS];
    __shared__ int            s_hist[K];
    __shared__ int            s_pref[K];
    __shared__ int            s_cur[K];

    const int tid = threadIdx.x;
    const long long base = (long long)blockIdx.x * NPTS;
    int npts = (int)((long long)N - base);
    if (npts > NPTS) npts = NPTS;

    if (blockIdx.x == 0)                       // zero global accumulator
        for (int e = tid; e < P1; e += 256) sums[e] = 0.f;

    if (tid < K) s_hist[tid] = 0;
    __syncthreads();

    // stage labels (coalesced int4) + histogram (1 int atomic per point)
    const int n4 = npts >> 2;
    for (int i4 = tid; i4 < n4; i4 += 256) {
        const int4 v = ((const int4*)(lab + base))[i4];
        s_lab[i4 * 4 + 0] = v.x; s_lab[i4 * 4 + 1] = v.y;
        s_lab[i4 * 4 + 2] = v.z; s_lab[i4 * 4 + 3] = v.w;
        atomicAdd(&s_hist[v.x], 1); atomicAdd(&s_hist[v.y], 1);
        atomicAdd(&s_hist[v.z], 1); atomicAdd(&s_hist[v.w], 1);
    }
    for (int i = (n4 << 2) + tid; i < npts; i += 256) {  // tail
        const int l = lab[base + i];
        s_lab[i] = l;
        atomicAdd(&s_hist[l], 1);
    }
    __syncthreads();

    // exclusive prefix over 64 bins (wave 0)
    if (tid < 64) {
        const int h = s_hist[tid];
        int v = h;
        for (int off = 1; off < 64; off <<= 1) {
            const int up = __shfl_up(v, off);
            if (tid >= off) v += up;
        }
        s_pref[tid] = v - h;
        s_cur[tid]  = v - h;
    }
    __syncthreads();

    // scatter sorted indices (1 int atomic per point)
    for (int i = tid; i < npts; i += 256) {
        const int l = s_lab[i];
        const int pos = atomicAdd(&s_cur[l], 1);
        s_idx[pos] = (unsigned short)i;
    }
    __syncthreads();

    // register accumulation: thread owns cluster k = tid>>2, dims q*8..q*8+7
    const int k = tid >> 2, q = tid & 3;
    const int start = s_pref[k], len = s_hist[k];
    float4 a0 = {0.f, 0.f, 0.f, 0.f}, a1 = {0.f, 0.f, 0.f, 0.f};
    int i = 0;
    for (; i + 4 <= len; i += 4) {            // unroll x4: 8 loads in flight
        const int i0 = s_idx[start + i + 0];
        const int i1 = s_idx[start + i + 1];
        const int i2 = s_idx[start + i + 2];
        const int i3 = s_idx[start + i + 3];
        const float4* r0 = (const float4*)(feat + (base + i0) * D + q * 8);
        const float4* r1 = (const float4*)(feat + (base + i1) * D + q * 8);
        const float4* r2 = (const float4*)(feat + (base + i2) * D + q * 8);
        const float4* r3 = (const float4*)(feat + (base + i3) * D + q * 8);
        const float4 x0 = r0[0], y0 = r0[1];
        const float4 x1 = r1[0], y1 = r1[1];
        const float4 x2 = r2[0], y2 = r2[1];
        const float4 x3 = r3[0], y3 = r3[1];
        a0.x += (x0.x + x1.x) + (x2.x + x3.x);
        a0.y += (x0.y + x1.y) + (x2.y + x3.y);
        a0.z += (x0.z + x1.z) + (x2.z + x3.z);
        a0.w += (x0.w + x1.w) + (x2.w + x3.w);
        a1.x += (y0.x + y1.x) + (y2.x + y3.x);
        a1.y += (y0.y + y1.y) + (y2.y + y3.y);
        a1.z += (y0.z + y1.z) + (y2.z + y3.z);
        a1.w += (y0.w + y1.w) + (y2.w + y3.w);
    }
    for (; i < len; ++i) {
        const int i0 = s_idx[start + i];
        const float4* r0 = (const float4*)(feat + (base + i0) * D + q * 8);
        const float4 x0 = r0[0], y0 = r0[1];
        a0.x += x0.x; a0.y += x0.y; a0.z += x0.z; a0.w += x0.w;
        a1.x += y0.x; a1.y += y0.y; a1.z += y0.z; a1.w += y0.w;
    }
    float* outp = part1 + (long long)blockIdx.x * P1;
    ((float4*)outp)[tid * 2 + 0] = a0;        // cell k*32 + q*8 == tid*8
    ((float4*)outp)[tid * 2 + 1] = a1;
    if (tid < K) outp[K * D + tid] = (float)s_hist[tid];
}

// ------- reduce: chunk-partials -> fire-and-forget atomics into sums -------
__global__ __launch_bounds__(256) void reduce1_kernel(
    const float* __restrict__ part1, float* __restrict__ sums,
    int chsz, int nblk1)
{
    const int e = blockIdx.x * 256 + threadIdx.x;
    if (e >= P1) return;
    const int y = blockIdx.y;
    const int b0 = y * chsz;
    int b1 = b0 + chsz; if (b1 > nblk1) b1 = nblk1;
    float s = 0.f;
    for (int b = b0; b < b1; b++) s += part1[(long long)b * P1 + e];
    atomicAdd(&sums[e], s);                   // non-returning, 64 contenders
}

// ---------------- pass 2: means-from-sums prologue + hinge + block0 epi ----
__global__ __launch_bounds__(256, 4) void pass2_kernel(
    const float* __restrict__ feat, const int* __restrict__ lab,
    const float* __restrict__ sums,
    float* __restrict__ hpart, float* __restrict__ ir, int N)
{
    __shared__ float s_m[K * MPAD];   // padded means, 10 KB
    __shared__ float s_ic[K];
    __shared__ float s_red[256];
    const int tid = threadIdx.x;

    for (int e = tid; e < K * D; e += 256) {          // means = sums / cnt
        const float c = sums[K * D + (e >> 5)];       // broadcast line, L2-hot
        s_m[(e >> 5) * MPAD + (e & 31)] = sums[e] / fmaxf(c, 1.0f);
    }
    if (tid < K) s_ic[tid] = 1.0f / fmaxf(sums[K * D + tid], 1.0f);
    __syncthreads();

    float racc = 0.f;
    const long long stride = (long long)NBLK2 * 256;
    for (long long p = (long long)blockIdx.x * 256 + tid; p < N; p += stride) {
        const int l = lab[p];
        const float4* frow = (const float4*)(feat + p * D);
        float4 fv[8];
        #pragma unroll
        for (int j = 0; j < 8; j++) fv[j] = frow[j];   // 8 loads in flight
        const float* mrow = s_m + l * MPAD;
        float d2 = 0.f;
        #pragma unroll
        for (int j = 0; j < 8; j++) {
            const float4 mv = *(const float4*)(mrow + j * 4);
            const float dx = fv[j].x - mv.x + EPS_F;
            const float dy = fv[j].y - mv.y + EPS_F;
            const float dz = fv[j].z - mv.z + EPS_F;
            const float dw = fv[j].w - mv.w + EPS_F;
            d2 += dx * dx + dy * dy + dz * dz + dw * dw;
        }
        const float h = fmaxf(sqrtf(d2) - 1.5f, 0.f);  // INTRA_MARGIN_USED
        racc += h * h * s_ic[l];
    }
    s_red[tid] = racc;
    __syncthreads();
    for (int st = 128; st; st >>= 1) { if (tid < st) s_red[tid] += s_red[tid + st]; __syncthreads(); }
    if (tid == 0) hpart[blockIdx.x] = s_red[0];

    if (blockIdx.x != 0) return;
    // ---- block 0 epilogue: inter + reg from s_m (overlaps other blocks) ----
    __syncthreads();
    float mj[32];
    const int j = tid & 63;
    #pragma unroll
    for (int d = 0; d < 32; d++) mj[d] = s_m[j * MPAD + d];
    float isum = 0.f;
    const int igrp = tid >> 6;        // 0..3, 16 i's each; i wave-uniform
    for (int ii = 0; ii < 16; ii++) {
        const int i = igrp * 16 + ii;
        const float4* srow = (const float4*)(s_m + i * MPAD);
        float d2 = 0.f;
        #pragma unroll
        for (int q = 0; q < 8; q++) {
            const float4 mv = srow[q];
            const float b0 = mv.x - mj[q * 4 + 0] + EPS_F;
            const float b1 = mv.y - mj[q * 4 + 1] + EPS_F;
            const float b2 = mv.z - mj[q * 4 + 2] + EPS_F;
            const float b3 = mv.w - mj[q * 4 + 3] + EPS_F;
            d2 += b0 * b0 + b1 * b1 + b2 * b2 + b3 * b3;
        }
        if (i != j) {
            const float h = fmaxf(1.0f - sqrtf(d2), 0.f);  // 2*margin - pd
            isum += h * h;
        }
    }
    s_red[tid] = isum;
    __syncthreads();
    for (int st = 128; st; st >>= 1) { if (tid < st) s_red[tid] += s_red[tid + st]; __syncthreads(); }
    if (tid == 0) ir[0] = s_red[0] * (1.0f / ((K - 1) * K));
    __syncthreads();

    float r = 0.f;
    if (tid < 64) {
        float d2 = 0.f;
        #pragma unroll
        for (int d = 0; d < 32; d++) { const float t = mj[d] + EPS_F; d2 += t * t; }
        r = sqrtf(d2);
    }
    s_red[tid] = r;
    __syncthreads();
    for (int st = 128; st; st >>= 1) { if (tid < st) s_red[tid] += s_red[tid + st]; __syncthreads(); }
    if (tid == 0) ir[1] = s_red[0] * (1.0f / K);
}

// ---------------- final: hpart sum + combine --------------------------------
__global__ __launch_bounds__(256) void final_kernel(
    const float* __restrict__ hpart, const float* __restrict__ ir,
    float* __restrict__ out)
{
    __shared__ float s_red[256];
    const int tid = threadIdx.x;
    float hs = 0.f;
    for (int b = tid; b < NBLK2; b += 256) hs += hpart[b];
    s_red[tid] = hs;
    __syncthreads();
    for (int st = 128; st; st >>= 1) { if (tid < st) s_red[tid] += s_red[tid + st]; __syncthreads(); }
    if (tid == 0) out[0] = s_red[0] * (1.0f / K) + ir[0] + 0.001f * ir[1];
}

extern "C" void kernel_launch(void* const* d_in, const int* in_sizes, int n_in,
                              void* d_out, int out_size, void* d_ws, size_t ws_size,
                              hipStream_t stream)
{
    const float* feat = (const float*)d_in[0];
    const int*   lab  = (const int*)d_in[1];
    const int N = in_sizes[1];            // 1e6; D=32, K=64 fixed by reference

    float* ws = (float*)d_ws;

    const int nblk1 = (N + NPTS - 1) / NPTS;         // 977
    const int chsz  = (nblk1 + NCH - 1) / NCH;       // 16

    float* sums  = ws;                               // P1 (sums + counts)
    float* ir    = sums + P1;                        // 2 (+pad 2)
    float* hpart = ir + 4;                           // NBLK2
    float* part1 = hpart + NBLK2;                    // nblk1*P1

    pass1_kernel<<<nblk1, 256, 0, stream>>>(feat, lab, part1, sums, N);
    reduce1_kernel<<<dim3((P1 + 255) / 256, NCH), 256, 0, stream>>>(part1, sums, chsz, nblk1);
    pass2_kernel<<<NBLK2, 256, 0, stream>>>(feat, lab, sums, hpart, ir, N);
    final_kernel<<<1, 256, 0, stream>>>(hpart, ir, (float*)d_out);
}